// Round 16
// baseline (369.362 us; speedup 1.0000x reference)
//
#include <hip/hip_runtime.h>
#include <math.h>

#define H 128

typedef unsigned short u16;
typedef unsigned int u32;
typedef __attribute__((ext_vector_type(4))) u32 u32x4;
typedef __attribute__((ext_vector_type(8))) __bf16 bf16x8;
typedef __attribute__((ext_vector_type(4))) float f32x4;
typedef __attribute__((ext_vector_type(16))) float f32x16;

union Frag { u32x4 u; bf16x8 b; };

// f32 pair -> packed bf16 (RNE). Native __bf16 casts: compiler emits
// v_cvt_pk_bf16_f32 (1 instr) instead of the ~7-instr software RNE path.
__device__ __forceinline__ u32 pack2(float lo, float hi) {
    union { __bf16 b[2]; u32 u; } v;
    v.b[0] = (__bf16)lo; v.b[1] = (__bf16)hi;
    return v.u;
}
__device__ __forceinline__ float bflo(u32 w) {           // low bf16 -> f32
    union { u32 i; float f; } v; v.i = w << 16; return v.f;
}
__device__ __forceinline__ float bfhi(u32 w) {           // high bf16 -> f32
    union { u32 i; float f; } v; v.i = w & 0xffff0000u; return v.f;
}
__device__ __forceinline__ float silu(float v) {
    float e = __expf(-v);
    return v * __builtin_amdgcn_rcpf(1.0f + e);
}
__device__ __forceinline__ bf16x8 f8frag(float4 lo, float4 hi) {
    Frag f;
    f.u = (u32x4){pack2(lo.x, lo.y), pack2(lo.z, lo.w),
                  pack2(hi.x, hi.y), pack2(hi.z, hi.w)};
    return f.b;
}
__device__ __forceinline__ f32x16 mfma(bf16x8 a, bf16x8 b, f32x16 c) {
    return __builtin_amdgcn_mfma_f32_32x32x16_bf16(a, b, c, 0, 0, 0);
}
__device__ __forceinline__ f32x4 mfma16(bf16x8 a, bf16x8 b, f32x4 c) {
    return __builtin_amdgcn_mfma_f32_16x16x32_bf16(a, b, c, 0, 0, 0);
}
// VALU-pipe cross-lane add within 16-lane rows: v += row_ror(v, N)
#define DPP_RADD(v, ctrl) \
    (v) += __int_as_float(__builtin_amdgcn_update_dpp(0, __float_as_int(v), (ctrl), 0xf, 0xf, 1))

// ---------------------------------------------------------------------------
// ws frag region (u32 units):
//   mw1s @ 0      : 4ct x 17kb x 64lane x 4   (msg w1^T 32x32 frags; kb16 = dist+b1)
//   mw2s @ 17408  : 4ct x  9kb x 64lane x 4   (msg w2^T 32x32 frags; kb8 = b2)
//   uw1s @ 26624  : 4ct x 17kb x 64lane x 4   (upd w1^T 32x32 frags; kb16 = b1)
//   uw2s @ 44032  : 4ct x  9kb x 64lane x 4   (upd w2^T 32x32 frags; kb8 = b2)
//   m16s @ 53248  : 5kb x 8mt x 64lane x 4    (msg w2 16x16 A-frags)
//   wdp  @ 63488  : 64 u32                    (dist-row weights packed bf16)
// ---------------------------------------------------------------------------
__global__ void prep_kernel(const float* __restrict__ mw1, const float* __restrict__ mb1,
                            const float* __restrict__ mw2, const float* __restrict__ mb2,
                            const float* __restrict__ uw1, const float* __restrict__ ub1,
                            const float* __restrict__ uw2, const float* __restrict__ ub2,
                            u32* __restrict__ ws) {
    int t = blockIdx.x * blockDim.x + threadIdx.x;
    if (t >= 15936) return;
    if (t >= 15872) {
        // ---- dist-row weights, packed bf16 ----
        int i = t - 15872;                    // [0, 64)
        ws[63488 + i] = pack2(mw1[256 * H + 2 * i], mw1[256 * H + 2 * i + 1]);
        return;
    }
    if (t >= 13312) {
        // ---- 16x16 A-frags of msg w2 ----
        int slot = t - 13312;                 // (kb*8 + mt)*64 + lane
        int lane = slot & 63, fb = slot >> 6;
        int kb = fb >> 3, mt = fb & 7;
        int m = mt * 16 + (lane & 15);
        int quad = lane >> 4;
        u32 out[4];
        #pragma unroll
        for (int p = 0; p < 4; ++p) {
            float v[2];
            #pragma unroll
            for (int h = 0; h < 2; ++h) {
                int k = kb * 32 + quad * 8 + p * 2 + h;
                float val = 0.0f;
                if (k < 128)       val = mw2[(size_t)k * H + m];
                else if (k == 128) val = mb2[m];
                v[h] = val;
            }
            out[p] = pack2(v[0], v[1]);
        }
        u32* dst = ws + 53248 + (size_t)slot * 4;
        dst[0] = out[0]; dst[1] = out[1]; dst[2] = out[2]; dst[3] = out[3];
        return;
    }
    const float *W, *s0, *s1;
    int nK, slot, base;
    if (t < 4352)       { W = mw1; s0 = mw1 + 256 * H; s1 = mb1; nK = 256; slot = t;         base = 0;     }
    else if (t < 6656)  { W = mw2; s0 = mb2; s1 = nullptr;       nK = 128; slot = t - 4352;  base = 17408; }
    else if (t < 11008) { W = uw1; s0 = ub1; s1 = nullptr;       nK = 256; slot = t - 6656;  base = 26624; }
    else                { W = uw2; s0 = ub2; s1 = nullptr;       nK = 128; slot = t - 11008; base = 44032; }
    int lane = slot & 63, fb = slot >> 6;
    int ct, kb;
    if (nK == 256) { ct = fb / 17; kb = fb % 17; }
    else           { ct = fb / 9;  kb = fb % 9;  }
    int m = ct * 32 + (lane & 31);
    int q = lane >> 5;
    u32 out[4];
    #pragma unroll
    for (int p = 0; p < 4; ++p) {
        float v[2];
        #pragma unroll
        for (int h = 0; h < 2; ++h) {
            int k = kb * 16 + q * 8 + p * 2 + h;
            float val = 0.0f;
            if (k < nK)            val = W[(size_t)k * H + m];
            else if (k == nK)      val = s0 ? s0[m] : 0.0f;
            else if (k == nK + 1)  val = s1 ? s1[m] : 0.0f;
            v[h] = val;
        }
        out[p] = pack2(v[0], v[1]);
    }
    u32* dst = ws + base + (size_t)slot * 4;
    dst[0] = out[0]; dst[1] = out[1]; dst[2] = out[2]; dst[3] = out[3];
}

// ---------------------------------------------------------------------------
// front_kernel (R15: FOUR parallel jobs — R9's parallel fusion, extended):
//   blocks [0, PQB)        : P GEMM  (x @ mw1[0:128], packed bf16 -> Pb)
//   blocks [PQB, 2*PQB)    : Q GEMM  (x @ mw1[128:256] + b1, packed -> Qb)
//   blocks [2*PQB, 3*PQB)  : U GEMM  (x @ uw1[0:128], packed -> Ub)
//   blocks [3*PQB, +BKB)   : bucket_fill (grid-stride over E edges)
// ---------------------------------------------------------------------------
__global__ __launch_bounds__(256, 2) void front_kernel(
    const float* __restrict__ x, const u32* __restrict__ ws,
    u32* __restrict__ Pb, u32* __restrict__ Qb, u32* __restrict__ Ub,
    const float* __restrict__ pos, const int* __restrict__ ei,
    int* __restrict__ deg, int2* __restrict__ bucket,
    int N, int E, int nIter, int PQB, int BKB)
{
    const int b = blockIdx.x;
    if (b < 3 * PQB) {
        // ---- P / Q / U GEMM (pq_gemm body, 32 nodes/wave) ----
        const int job = b / PQB;                 // 0=P, 1=Q, 2=U
        const int bb = b - job * PQB;
        const int kbBase = (job == 1) ? 8 : 0;
        const u32* wt = (job == 2) ? (ws + 26624) : ws;   // U uses uw1 frags
        u32* outb = (job == 0) ? Pb : ((job == 1) ? Qb : Ub);

        const int lane = threadIdx.x & 63;
        const int q = lane >> 5, el = lane & 31;
        const int gw  = bb * 4 + (threadIdx.x >> 6);
        const int gws = PQB * 4;

        for (int it = gw; it < nIter; it += gws) {
            const int nA = it * 32 + el;
            const int ncA = (nA < N) ? nA : (N - 1);
            const float* xA = x + (size_t)ncA * H;

            f32x16 acc[4];
            #pragma unroll
            for (int ct = 0; ct < 4; ++ct) acc[ct] = (f32x16)0.0f;

            #pragma unroll
            for (int kb = 0; kb < 8; ++kb) {
                const int f = kb * 16 + q * 8;
                bf16x8 bA = f8frag(*(const float4*)(xA + f), *(const float4*)(xA + f + 4));
                #pragma unroll
                for (int ct = 0; ct < 4; ++ct) {
                    Frag a; a.u = *(const u32x4*)&wt[((size_t)(ct * 17 + kbBase + kb) * 64 + lane) * 4];
                    acc[ct] = mfma(a.b, bA, acc[ct]);
                }
            }
            if (job == 1) {   // Q bias: pad kb16 (k=256 -> 0 skip dist, k=257 -> 1.0 b1)
                Frag bp; bp.u = (u32x4){0, 0, 0, 0};
                if (q == 0) bp.u.x = pack2(0.0f, 1.0f);
                #pragma unroll
                for (int ct = 0; ct < 4; ++ct) {
                    Frag a; a.u = *(const u32x4*)&ws[((size_t)(ct * 17 + 16) * 64 + lane) * 4];
                    acc[ct] = mfma(a.b, bp.b, acc[ct]);
                }
            }
            if (nA < N) {
                u32* prow = outb + (size_t)nA * 64;
                #pragma unroll
                for (int ct = 0; ct < 4; ++ct)
                    #pragma unroll
                    for (int g = 0; g < 4; ++g) {
                        u32 a = pack2(acc[ct][4*g + 0], acc[ct][4*g + 1]);
                        u32 bb2 = pack2(acc[ct][4*g + 2], acc[ct][4*g + 3]);
                        *(uint2*)(prow + ct * 16 + 4 * g + 2 * q) = make_uint2(a, bb2);
                    }
            }
        }
    } else {
        // ---- bucket_fill: grid-stride over edges ----
        const int bb = b - 3 * PQB;
        for (int e = bb * 256 + (int)threadIdx.x; e < E; e += BKB * 256) {
            const int s = ei[e];
            const int r = ei[E + e];
            const float dx = pos[s*3]   - pos[r*3];
            const float dy = pos[s*3+1] - pos[r*3+1];
            const float dz = pos[s*3+2] - pos[r*3+2];
            const float dist = sqrtf(dx*dx + dy*dy + dz*dz);
            int slot = atomicAdd(&deg[r], 1);
            if (slot < 64) bucket[(size_t)r * 64 + slot] = make_int2(s, __float_as_int(dist));
        }
    }
}

// ---------------------------------------------------------------------------
// One 16-edge tile of the aggregate: acc init = b2, 4 kb steps of
// h=silu(P+Q+dist*wd) -> MFMA, masked silu accumulation into sum.
// ---------------------------------------------------------------------------
__device__ __forceinline__ void agg_tile(
    const u32x4 pc[4], const u32x4* __restrict__ Qrow,
    const u32x4* __restrict__ wds, const u32x4* __restrict__ af,
    const float* __restrict__ b2s, float dist, bool valid,
    int lane, int quad, f32x4 sum[8])
{
    f32x4 acc[8];
    #pragma unroll
    for (int mt = 0; mt < 8; ++mt)
        acc[mt] = *(const f32x4*)&b2s[mt * 16 + quad * 4];

    #pragma unroll 2
    for (int kb = 0; kb < 4; ++kb) {
        const u32x4 p = pc[kb];
        const u32x4 qc = Qrow[kb * 4 + quad];
        const u32x4 wc = wds[kb * 4 + quad];
        const float v0 = silu(bflo(p.x) + bflo(qc.x) + dist * bflo(wc.x));
        const float v1 = silu(bfhi(p.x) + bfhi(qc.x) + dist * bfhi(wc.x));
        const float v2 = silu(bflo(p.y) + bflo(qc.y) + dist * bflo(wc.y));
        const float v3 = silu(bfhi(p.y) + bfhi(qc.y) + dist * bfhi(wc.y));
        const float v4 = silu(bflo(p.z) + bflo(qc.z) + dist * bflo(wc.z));
        const float v5 = silu(bfhi(p.z) + bfhi(qc.z) + dist * bfhi(wc.z));
        const float v6 = silu(bflo(p.w) + bflo(qc.w) + dist * bflo(wc.w));
        const float v7 = silu(bfhi(p.w) + bfhi(qc.w) + dist * bfhi(wc.w));
        Frag bf;
        bf.u = (u32x4){pack2(v0, v1), pack2(v2, v3), pack2(v4, v5), pack2(v6, v7)};
        if (!valid) bf.u = (u32x4){0, 0, 0, 0};
        #pragma unroll
        for (int mt = 0; mt < 8; ++mt) {
            Frag a; a.u = af[(kb * 8 + mt) * 64 + lane];
            acc[mt] = mfma16(a.b, bf.b, acc[mt]);
        }
    }
    #pragma unroll
    for (int mt = 0; mt < 8; ++mt) {
        sum[mt][0] += valid ? silu(acc[mt][0]) : 0.0f;
        sum[mt][1] += valid ? silu(acc[mt][1]) : 0.0f;
        sum[mt][2] += valid ? silu(acc[mt][2]) : 0.0f;
        sum[mt][3] += valid ? silu(acc[mt][3]) : 0.0f;
    }
}

// ---------------------------------------------------------------------------
// aggregate (16x16, R16: TWO nodes per wave — chain-level ILP).
// R15 model: per-node serial chain deg->bucket->P-gather (~1000cy) + ~500cy
// compute; at 2 eff. waves/SIMD utilization = 2*500/1500 = 67% ~= measured
// 61% VALUBusy. R6's prefetch nulled because it skipped the P-gather hop.
// Fix: pair nodes per wave; both bucket reads + both P-row gathers issue
// back-to-back, B's gathers return under A's compute.
// Reg budget: sumA/B 64 + pcA/B 32 + misc ~30 = ~126 arch + 32 acc < ~170
// cap @(256,3). Sentinels: VGPR <= ~140, WRITE stays 12.5 MB (spill => revert).
// ---------------------------------------------------------------------------
__global__ __launch_bounds__(256, 3) void aggregate_kernel(
    const u32* __restrict__ Pbf, const u32* __restrict__ Qbf,
    const u32* __restrict__ wdp, const u32* __restrict__ ws16,
    const float* __restrict__ mb2,
    const int* __restrict__ deg, const int2* __restrict__ bucket,
    u32* __restrict__ aggrp, int N)
{
    __shared__ u32x4 af[2048];                        // 32 KiB: w2 16x16 A-frags
    __shared__ float b2s[128];                        // b2 fp32 (C-init source)
    __shared__ u32x4 wds[16];                         // dist-row weights (packed bf16)
    for (int i = threadIdx.x; i < 2048; i += 256) af[i] = ((const u32x4*)ws16)[i];
    for (int i = threadIdx.x; i < 128; i += 256) b2s[i] = mb2[i];
    if (threadIdx.x < 16) wds[threadIdx.x] = ((const u32x4*)wdp)[threadIdx.x];
    __syncthreads();

    const int lane = threadIdx.x & 63;
    const int quad = lane >> 4, col = lane & 15;

    const int gw  = blockIdx.x * 4 + (threadIdx.x >> 6);
    const int gws = gridDim.x * 4;
    const int nPairs = (N + 1) >> 1;

    for (int pr = gw; pr < nPairs; pr += gws) {
        const int na = pr * 2;
        const int nb = na + 1;
        const bool hasB = nb < N;

        int dna = deg[na]; dna = (dna > 64) ? 64 : dna;
        int dnb = hasB ? deg[nb] : 0; dnb = (dnb > 64) ? 64 : dnb;
        const int nta = (dna + 15) >> 4;
        const int ntb = (dnb + 15) >> 4;
        const int ntm = (nta > ntb) ? nta : ntb;

        const u32x4* QrowA = (const u32x4*)(Qbf + (size_t)na * 64);
        const u32x4* QrowB = (const u32x4*)(Qbf + (size_t)(hasB ? nb : na) * 64);

        f32x4 sumA[8], sumB[8];
        #pragma unroll
        for (int mt = 0; mt < 8; ++mt) {
            sumA[mt] = (f32x4){0.f, 0.f, 0.f, 0.f};
            sumB[mt] = (f32x4){0.f, 0.f, 0.f, 0.f};
        }

        for (int t = 0; t < ntm; ++t) {
            const int eIdx = t * 16 + col;
            const bool doA = t < nta;
            const bool doB = t < ntb;

            // ---- issue BOTH chains' loads up front (latency overlap) ----
            u32x4 pcA[4], pcB[4];
            float distA = 0.0f, distB = 0.0f;
            bool validA = false, validB = false;
            if (doA) {                                    // wave-uniform branch
                validA = eIdx < dna;
                const int eC = validA ? eIdx : (dna - 1);
                const int2 rec = bucket[(size_t)na * 64 + eC];
                const u32x4* Prow = (const u32x4*)(Pbf + (size_t)rec.x * 64);
                distA = __int_as_float(rec.y);
                #pragma unroll
                for (int kb = 0; kb < 4; ++kb) pcA[kb] = Prow[kb * 4 + quad];
            }
            if (doB) {                                    // wave-uniform branch
                validB = eIdx < dnb;
                const int eC = validB ? eIdx : (dnb - 1);
                const int2 rec = bucket[(size_t)nb * 64 + eC];
                const u32x4* Prow = (const u32x4*)(Pbf + (size_t)rec.x * 64);
                distB = __int_as_float(rec.y);
                #pragma unroll
                for (int kb = 0; kb < 4; ++kb) pcB[kb] = Prow[kb * 4 + quad];
            }

            // ---- compute A then B (B's loads arrive under A's compute) ----
            if (doA) agg_tile(pcA, QrowA, wds, af, b2s, distA, validA, lane, quad, sumA);
            if (doB) agg_tile(pcB, QrowB, wds, af, b2s, distB, validB, lane, quad, sumB);
        }

        // reduce over the 16 column-lanes: DPP row rotations, pure VALU
        #pragma unroll
        for (int mt = 0; mt < 8; ++mt)
            #pragma unroll
            for (int r = 0; r < 4; ++r) {
                float va = sumA[mt][r];
                DPP_RADD(va, 0x128); DPP_RADD(va, 0x124);
                DPP_RADD(va, 0x122); DPP_RADD(va, 0x121);
                sumA[mt][r] = va;
                float vb = sumB[mt][r];
                DPP_RADD(vb, 0x128); DPP_RADD(vb, 0x124);
                DPP_RADD(vb, 0x122); DPP_RADD(vb, 0x121);
                sumB[mt][r] = vb;
            }
        if (col == 0) {               // lanes 0,16,32,48: dims mt*16+quad*4+j
            u32* orowA = aggrp + (size_t)na * 64;
            #pragma unroll
            for (int mt = 0; mt < 8; ++mt) {
                u32 a = pack2(sumA[mt][0], sumA[mt][1]);
                u32 b = pack2(sumA[mt][2], sumA[mt][3]);
                *(uint2*)(orowA + mt * 8 + quad * 2) = make_uint2(a, b);
            }
            if (hasB) {
                u32* orowB = aggrp + (size_t)nb * 64;
                #pragma unroll
                for (int mt = 0; mt < 8; ++mt) {
                    u32 a = pack2(sumB[mt][0], sumB[mt][1]);
                    u32 b = pack2(sumB[mt][2], sumB[mt][3]);
                    *(uint2*)(orowB + mt * 8 + quad * 2) = make_uint2(a, b);
                }
            }
        }
    }
}

// ---------------------------------------------------------------------------
// node1_slim (R15): h = silu(U + aggr @ uw1[128:256] + b1) -> packed bf16.
// ---------------------------------------------------------------------------
__global__ __launch_bounds__(256, 2) void node1_slim(
    const u32* __restrict__ aggrp, const u32* __restrict__ Ub,
    const u32* __restrict__ ws, u32* __restrict__ Hb, int N, int nIter)
{
    __shared__ u32 lds[8192];                         // uw1 kb 8..15 frags (32 KiB)
    const u32* wsl1 = ws + 26624;
    {
        const u32x4* src = (const u32x4*)wsl1;
        u32x4* dst = (u32x4*)lds;
        for (int i = threadIdx.x; i < 2048; i += 256) {
            int ln = i & 63, fb = i >> 6, ct = fb >> 3, kb = fb & 7;
            dst[i] = src[(ct * 17 + 8 + kb) * 64 + ln];
        }
    }
    __syncthreads();

    const int lane = threadIdx.x & 63;
    const int q = lane >> 5, el = lane & 31;
    const int gw  = blockIdx.x * 4 + (threadIdx.x >> 6);
    const int gws = gridDim.x * 4;

    for (int it = gw; it < nIter; it += gws) {
        const int nA = it * 32 + el;
        const int ncA = (nA < N) ? nA : (N - 1);
        const u32* arow = aggrp + (size_t)ncA * 64;
        const u32* Urow = Ub + (size_t)ncA * 64;

        f32x16 acc[4];
        #pragma unroll
        for (int ct = 0; ct < 4; ++ct) acc[ct] = (f32x16)0.0f;

        #pragma unroll
        for (int kb = 0; kb < 8; ++kb) {
            Frag hb; hb.u = *(const u32x4*)&arow[kb * 8 + q * 4];
            #pragma unroll
            for (int ct = 0; ct < 4; ++ct) {
                Frag a; a.u = *(const u32x4*)&lds[((ct * 8 + kb) * 64 + lane) * 4];
                acc[ct] = mfma(a.b, hb.b, acc[ct]);
            }
        }
        {   // bias: k=256 -> 1.0 (b1)
            Frag bp; bp.u = (u32x4){0,0,0,0};
            if (q == 0) bp.u.x = 0x00003F80u;
            #pragma unroll
            for (int ct = 0; ct < 4; ++ct) {
                Frag a; a.u = *(const u32x4*)&wsl1[((size_t)(ct * 17 + 16) * 64 + lane) * 4];
                acc[ct] = mfma(a.b, bp.b, acc[ct]);
            }
        }
        if (nA < N) {
            u32* hrow = Hb + (size_t)nA * 64;
            #pragma unroll
            for (int ct = 0; ct < 4; ++ct)
                #pragma unroll
                for (int g = 0; g < 4; ++g) {
                    uint2 uv = *(const uint2*)&Urow[ct * 16 + 4 * g + 2 * q];
                    u32 a = pack2(silu(acc[ct][4*g + 0] + bflo(uv.x)),
                                  silu(acc[ct][4*g + 1] + bfhi(uv.x)));
                    u32 b = pack2(silu(acc[ct][4*g + 2] + bflo(uv.y)),
                                  silu(acc[ct][4*g + 3] + bfhi(uv.y)));
                    *(uint2*)(hrow + ct * 16 + 4 * g + 2 * q) = make_uint2(a, b);
                }
        }
    }
}

// ---------------------------------------------------------------------------
// node1_full (fallback path only): h = silu([x,aggr]@uw1+b1), f32 aggr input.
// ---------------------------------------------------------------------------
__global__ __launch_bounds__(256, 2) void node1_full(
    const float* __restrict__ x, const float* __restrict__ aggr,
    const u32* __restrict__ ws, u32* __restrict__ Hb, int N, int nIter)
{
    __shared__ u32 lds[16384];
    const u32* wsl1 = ws + 26624;
    {
        const u32x4* src = (const u32x4*)wsl1;
        u32x4* dst = (u32x4*)lds;
        for (int i = threadIdx.x; i < 4096; i += 256) {
            int ln = i & 63, fb = i >> 6, ct = fb >> 4, kb = fb & 15;
            dst[i] = src[(ct * 17 + kb) * 64 + ln];
        }
    }
    __syncthreads();

    const int lane = threadIdx.x & 63;
    const int q = lane >> 5, el = lane & 31;
    const int gw  = blockIdx.x * 4 + (threadIdx.x >> 6);
    const int gws = gridDim.x * 4;

    for (int it = gw; it < nIter; it += gws) {
        const int nA = it * 32 + el;
        const int ncA = (nA < N) ? nA : (N - 1);
        const float* xA = x + (size_t)ncA * H;
        const float* gA = aggr + (size_t)ncA * H;

        f32x16 acc[4];
        #pragma unroll
        for (int ct = 0; ct < 4; ++ct) acc[ct] = (f32x16)0.0f;

        #pragma unroll
        for (int kb = 0; kb < 16; ++kb) {
            const int f = kb * 16 + q * 8;
            const float* pA = (f < H) ? (xA + f) : (gA + f - H);
            bf16x8 bA = f8frag(*(const float4*)pA, *(const float4*)(pA + 4));
            #pragma unroll
            for (int ct = 0; ct < 4; ++ct) {
                Frag a; a.u = *(const u32x4*)&lds[((ct * 16 + kb) * 64 + lane) * 4];
                acc[ct] = mfma(a.b, bA, acc[ct]);
            }
        }
        {
            Frag bp; bp.u = (u32x4){0,0,0,0};
            if (q == 0) bp.u.x = 0x00003F80u;
            #pragma unroll
            for (int ct = 0; ct < 4; ++ct) {
                Frag a; a.u = *(const u32x4*)&wsl1[((size_t)(ct * 17 + 16) * 64 + lane) * 4];
                acc[ct] = mfma(a.b, bp.b, acc[ct]);
            }
        }
        if (nA < N) {
            u32* hrow = Hb + (size_t)nA * 64;
            #pragma unroll
            for (int ct = 0; ct < 4; ++ct)
                #pragma unroll
                for (int g = 0; g < 4; ++g) {
                    u32 a = pack2(silu(acc[ct][4*g + 0]), silu(acc[ct][4*g + 1]));
                    u32 b = pack2(silu(acc[ct][4*g + 2]), silu(acc[ct][4*g + 3]));
                    *(uint2*)(hrow + ct * 16 + 4 * g + 2 * q) = make_uint2(a, b);
                }
        }
    }
}

// ---------------------------------------------------------------------------
// node2: update = h @ uw2 + b2 -> out (f32). B-frag = one u32x4 row load.
// ---------------------------------------------------------------------------
__global__ __launch_bounds__(256, 2) void node2_kernel(
    const u32* __restrict__ Hb, const u32* __restrict__ ws,
    float* __restrict__ out, int N, int nIter)
{
    const u32* wsl2 = ws + 44032;
    const int lane = threadIdx.x & 63;
    const int q = lane >> 5, el = lane & 31;
    const int gw  = blockIdx.x * 4 + (threadIdx.x >> 6);
    const int gws = gridDim.x * 4;

    for (int it = gw; it < nIter; it += gws) {
        const int nA = it * 32 + el;
        const int ncA = (nA < N) ? nA : (N - 1);
        const u32* hrow = Hb + (size_t)ncA * 64;

        f32x16 acc[4];
        #pragma unroll
        for (int ct = 0; ct < 4; ++ct) acc[ct] = (f32x16)0.0f;

        #pragma unroll
        for (int kb = 0; kb < 8; ++kb) {
            Frag hb; hb.u = *(const u32x4*)&hrow[kb * 8 + q * 4];
            #pragma unroll
            for (int ct = 0; ct < 4; ++ct) {
                Frag a; a.u = *(const u32x4*)&wsl2[((size_t)(ct * 9 + kb) * 64 + lane) * 4];
                acc[ct] = mfma(a.b, hb.b, acc[ct]);
            }
        }
        {   // bias: k=128 -> 1.0 (b2)
            Frag bf; bf.u = (u32x4){0,0,0,0};
            if (q == 0) bf.u.x = 0x00003F80u;
            #pragma unroll
            for (int ct = 0; ct < 4; ++ct) {
                Frag a; a.u = *(const u32x4*)&wsl2[((size_t)(ct * 9 + 8) * 64 + lane) * 4];
                acc[ct] = mfma(a.b, bf.b, acc[ct]);
            }
        }
        if (nA < N) {
            float* orow = out + (size_t)nA * H;
            #pragma unroll
            for (int ct = 0; ct < 4; ++ct)
                #pragma unroll
                for (int g = 0; g < 4; ++g) {
                    float4 v = { acc[ct][4*g + 0], acc[ct][4*g + 1],
                                 acc[ct][4*g + 2], acc[ct][4*g + 3] };
                    *(float4*)(orow + ct * 32 + 8 * g + 4 * q) = v;
                }
        }
    }
}

// ---------------------------------------------------------------------------
// FALLBACK (ws too small): edge kernel with fp32 atomics.
// ---------------------------------------------------------------------------
__global__ __launch_bounds__(256, 2) void edge_mfma(
    const float* __restrict__ x, const float* __restrict__ pos,
    const int* __restrict__ ei, const u32* __restrict__ ws,
    float* __restrict__ aggr, int E, int nIter)
{
    __shared__ u32 lds[16384];
    {
        const u32x4* src = (const u32x4*)ws;
        u32x4* dst = (u32x4*)lds;
        for (int i = threadIdx.x; i < 4096; i += 256) {
            int ln = i & 63, fb = i >> 6, ct = fb >> 4, kb = fb & 15;
            dst[i] = src[(ct * 17 + kb) * 64 + ln];
        }
    }
    __syncthreads();
    const u32* wsl1 = ws;
    const u32* wsl2 = ws + 17408;

    const int lane = threadIdx.x & 63;
    const int q = lane >> 5, el = lane & 31;
    const int gw  = blockIdx.x * 4 + (threadIdx.x >> 6);
    const int gws = gridDim.x * 4;

    for (int it = gw; it < nIter; it += gws) {
        const int e0 = it * 64;
        const int sA = ei[e0 + el],      rA = ei[E + e0 + el];
        const int sB = ei[e0 + 32 + el], rB = ei[E + e0 + 32 + el];
        float dA, dB;
        {
            float ax = pos[sA*3] - pos[rA*3], ay = pos[sA*3+1] - pos[rA*3+1], az = pos[sA*3+2] - pos[rA*3+2];
            dA = sqrtf(ax*ax + ay*ay + az*az);
            float bx = pos[sB*3] - pos[rB*3], by = pos[sB*3+1] - pos[rB*3+1], bz = pos[sB*3+2] - pos[rB*3+2];
            dB = sqrtf(bx*bx + by*by + bz*bz);
        }
        const float* xsA = x + (size_t)sA * H; const float* xrA = x + (size_t)rA * H;
        const float* xsB = x + (size_t)sB * H; const float* xrB = x + (size_t)rB * H;

        f32x16 acc[2][4];
        #pragma unroll
        for (int s = 0; s < 2; ++s)
            #pragma unroll
            for (int ct = 0; ct < 4; ++ct) acc[s][ct] = (f32x16)0.0f;

        #pragma unroll
        for (int kb = 0; kb < 16; ++kb) {
            const int f = kb * 16 + q * 8;
            const float* pA = (f < H) ? (xsA + f) : (xrA + f - H);
            const float* pB = (f < H) ? (xsB + f) : (xrB + f - H);
            bf16x8 bA = f8frag(*(const float4*)pA, *(const float4*)(pA + 4));
            bf16x8 bB = f8frag(*(const float4*)pB, *(const float4*)(pB + 4));
            #pragma unroll
            for (int ct = 0; ct < 4; ++ct) {
                Frag a; a.u = *(const u32x4*)&lds[((ct * 16 + kb) * 64 + lane) * 4];
                acc[0][ct] = mfma(a.b, bA, acc[0][ct]);
                acc[1][ct] = mfma(a.b, bB, acc[1][ct]);
            }
        }
        {
            Frag bA, bB;
            bA.u = (u32x4){0,0,0,0}; bB.u = (u32x4){0,0,0,0};
            if (q == 0) { bA.u.x = pack2(dA, 1.0f); bB.u.x = pack2(dB, 1.0f); }
            #pragma unroll
            for (int ct = 0; ct < 4; ++ct) {
                Frag a; a.u = *(const u32x4*)&wsl1[((size_t)(ct * 17 + 16) * 64 + lane) * 4];
                acc[0][ct] = mfma(a.b, bA.b, acc[0][ct]);
                acc[1][ct] = mfma(a.b, bB.b, acc[1][ct]);
            }
        }

        #pragma unroll
        for (int s = 0; s < 2; ++s) {
            const int ridx = s ? rB : rA;
            u32 hp[16][2];
            #pragma unroll
            for (int ct = 0; ct < 4; ++ct)
                #pragma unroll
                for (int g = 0; g < 4; ++g) {
                    hp[ct * 4 + g][0] = pack2(silu(acc[s][ct][4*g + 0]), silu(acc[s][ct][4*g + 1]));
                    hp[ct * 4 + g][1] = pack2(silu(acc[s][ct][4*g + 2]), silu(acc[s][ct][4*g + 3]));
                }

            f32x16 acc2[4];
            #pragma unroll
            for (int ct = 0; ct < 4; ++ct) acc2[ct] = (f32x16)0.0f;

            #pragma unroll
            for (int kb2 = 0; kb2 < 8; ++kb2) {
                const u32 e0v = hp[2 * kb2][0],     e1v = hp[2 * kb2][1];
                const u32 o0v = hp[2 * kb2 + 1][0], o1v = hp[2 * kb2 + 1][1];
                const u32 w0  = q ? o0v : e0v;
                const u32 w1v = q ? o1v : e1v;
                const u32 sv0 = q ? e0v : o0v;
                const u32 sv1 = q ? e1v : o1v;
                u32 r0 = (u32)__shfl((int)sv0, lane ^ 32);
                u32 r1 = (u32)__shfl((int)sv1, lane ^ 32);
                Frag bf;
                if (q == 0) bf.u = (u32x4){w0, w1v, r0, r1};
                else        bf.u = (u32x4){r0, r1, w0, w1v};
                #pragma unroll
                for (int ct2 = 0; ct2 < 4; ++ct2) {
                    Frag a; a.u = *(const u32x4*)&wsl2[((size_t)(ct2 * 9 + kb2) * 64 + lane) * 4];
                    acc2[ct2] = mfma(a.b, bf.b, acc2[ct2]);
                }
            }
            {
                Frag bf; bf.u = (u32x4){0,0,0,0};
                if (q == 0) bf.u.x = 0x00003F80u;
                #pragma unroll
                for (int ct2 = 0; ct2 < 4; ++ct2) {
                    Frag a; a.u = *(const u32x4*)&wsl2[((size_t)(ct2 * 9 + 8) * 64 + lane) * 4];
                    acc2[ct2] = mfma(a.b, bf.b, acc2[ct2]);
                }
            }
            float* arow = aggr + (size_t)ridx * H;
            #pragma unroll
            for (int ct2 = 0; ct2 < 4; ++ct2)
                #pragma unroll
                for (int r = 0; r < 16; ++r) {
                    int m = ct2 * 32 + (r & 3) + 8 * (r >> 2) + 4 * q;
                    atomicAdd(arow + m, silu(acc2[ct2][r]));
                }
        }
    }
}

extern "C" void kernel_launch(void* const* d_in, const int* in_sizes, int n_in,
                              void* d_out, int out_size, void* d_ws, size_t ws_size,
                              hipStream_t stream) {
    const float* x    = (const float*)d_in[0];
    const float* pos  = (const float*)d_in[1];
    const int*   ei   = (const int*)d_in[2];
    const float* mw1  = (const float*)d_in[3];
    const float* mb1  = (const float*)d_in[4];
    const float* mw2  = (const float*)d_in[5];
    const float* mb2  = (const float*)d_in[6];
    const float* uw1  = (const float*)d_in[7];
    const float* ub1  = (const float*)d_in[8];
    const float* uw2  = (const float*)d_in[9];
    const float* ub2  = (const float*)d_in[10];

    const int N = in_sizes[0] / H;
    const int E = in_sizes[2] / 2;

    // ws layout (u32 units) — unchanged (U lives in d_out high half)
    const size_t FRAGS = 53248 + 10240 + 64;     // 32x32 frags + 16x16 frags + wdp
    const size_t PO = FRAGS;                     // P: N*64 u32 (packed bf16 rows)
    const size_t QO = PO + (size_t)N * 64;       // Q: N*64 u32 (packed bf16 rows)
    const size_t DG = QO + (size_t)N * 64;       // deg: N int
    const size_t BK = DG + (size_t)N;            // bucket: N*64 int2
    const size_t ENDu = BK + (size_t)N * 128;
    const size_t need_bytes = ENDu * 4;

    u32* ws = (u32*)d_ws;
    prep_kernel<<<63, 256, 0, stream>>>(mw1, mb1, mw2, mb2, uw1, ub1, uw2, ub2, ws);

    float* buf = (float*)d_out;
    u32* bufu = (u32*)d_out;
    const int nIter32 = (N + 31) / 32;           // 32 nodes per wave

    if (ws_size >= need_bytes) {
        // ---- gather path: no fp32 atomics ----
        u32*   Pb    = ws + PO;
        u32*   Qb    = ws + QO;
        int*   deg   = (int*)(ws + DG);
        int2*  bkt   = (int2*)(ws + BK);
        u32*   aggrp = bufu;                     // low half of d_out (packed aggr)
        u32*   Ub    = bufu + (size_t)N * 64;    // high half of d_out (packed U)

        hipMemsetAsync(deg, 0, (size_t)N * sizeof(int), stream);

        // P || Q || U GEMMs || bucket_fill, one launch (parallel fusion)
        const int PQB = 392;                     // 392*4 = 1568 waves >= 1563 iters
        const int BKB = 640;
        front_kernel<<<3 * PQB + BKB, 256, 0, stream>>>(
            x, ws, Pb, Qb, Ub, pos, ei, deg, bkt, N, E, nIter32, PQB, BKB);

        // 2-node-ILP aggregate: 768 blocks = exactly 3/CU at (256,3)
        aggregate_kernel<<<768, 256, 0, stream>>>(Pb, Qb, ws + 63488, ws + 53248,
                                                  mb2, deg, bkt, aggrp, N);

        // slim node MLP: h = silu(U + aggr@uw1[128:] + b1); update = h@uw2+b2
        node1_slim<<<512, 256, 0, stream>>>(aggrp, Ub, ws, Pb, N, nIter32);
        node2_kernel<<<512, 256, 0, stream>>>(Pb, ws, buf, N, nIter32);
    } else {
        // ---- fallback: atomic scatter path + full node MLP ----
        hipMemsetAsync(buf, 0, (size_t)N * H * sizeof(float), stream);
        edge_mfma<<<512, 256, 0, stream>>>(x, pos, ei, ws, buf, E, E / 64);
        node1_full<<<512, 256, 0, stream>>>(x, buf, ws, ws + PO, N, nIter32);
        node2_kernel<<<512, 256, 0, stream>>>(ws + PO, ws, buf, N, nIter32);
    }
}

// Round 17
// 358.786 us; speedup vs baseline: 1.0295x; 1.0295x over previous
//
#include <hip/hip_runtime.h>
#include <math.h>

#define H 128

typedef unsigned short u16;
typedef unsigned int u32;
typedef __attribute__((ext_vector_type(4))) u32 u32x4;
typedef __attribute__((ext_vector_type(8))) __bf16 bf16x8;
typedef __attribute__((ext_vector_type(4))) float f32x4;
typedef __attribute__((ext_vector_type(16))) float f32x16;

union Frag { u32x4 u; bf16x8 b; };

// f32 pair -> packed bf16 (RNE). Native __bf16 casts: compiler emits
// v_cvt_pk_bf16_f32 (1 instr) instead of the ~7-instr software RNE path.
__device__ __forceinline__ u32 pack2(float lo, float hi) {
    union { __bf16 b[2]; u32 u; } v;
    v.b[0] = (__bf16)lo; v.b[1] = (__bf16)hi;
    return v.u;
}
__device__ __forceinline__ float bflo(u32 w) {           // low bf16 -> f32
    union { u32 i; float f; } v; v.i = w << 16; return v.f;
}
__device__ __forceinline__ float bfhi(u32 w) {           // high bf16 -> f32
    union { u32 i; float f; } v; v.i = w & 0xffff0000u; return v.f;
}
__device__ __forceinline__ float silu(float v) {
    float e = __expf(-v);
    return v * __builtin_amdgcn_rcpf(1.0f + e);
}
__device__ __forceinline__ bf16x8 f8frag(float4 lo, float4 hi) {
    Frag f;
    f.u = (u32x4){pack2(lo.x, lo.y), pack2(lo.z, lo.w),
                  pack2(hi.x, hi.y), pack2(hi.z, hi.w)};
    return f.b;
}
__device__ __forceinline__ f32x16 mfma(bf16x8 a, bf16x8 b, f32x16 c) {
    return __builtin_amdgcn_mfma_f32_32x32x16_bf16(a, b, c, 0, 0, 0);
}
__device__ __forceinline__ f32x4 mfma16(bf16x8 a, bf16x8 b, f32x4 c) {
    return __builtin_amdgcn_mfma_f32_16x16x32_bf16(a, b, c, 0, 0, 0);
}
// VALU-pipe cross-lane add within 16-lane rows: v += row_ror(v, N)
#define DPP_RADD(v, ctrl) \
    (v) += __int_as_float(__builtin_amdgcn_update_dpp(0, __float_as_int(v), (ctrl), 0xf, 0xf, 1))

// ---------------------------------------------------------------------------
// ws frag region (u32 units):
//   mw1s @ 0      : 4ct x 17kb x 64lane x 4   (msg w1^T 32x32 frags; kb16 = dist+b1)
//   mw2s @ 17408  : 4ct x  9kb x 64lane x 4   (msg w2^T 32x32 frags; kb8 = b2)
//   uw1s @ 26624  : 4ct x 17kb x 64lane x 4   (upd w1^T 32x32 frags; kb16 = b1)
//   uw2s @ 44032  : 4ct x  9kb x 64lane x 4   (upd w2^T 32x32 frags; kb8 = b2)
//   m16s @ 53248  : 5kb x 8mt x 64lane x 4    (msg w2 16x16 A-frags)
//   wdp  @ 63488  : 64 u32                    (dist-row weights packed bf16)
// ---------------------------------------------------------------------------
__global__ void prep_kernel(const float* __restrict__ mw1, const float* __restrict__ mb1,
                            const float* __restrict__ mw2, const float* __restrict__ mb2,
                            const float* __restrict__ uw1, const float* __restrict__ ub1,
                            const float* __restrict__ uw2, const float* __restrict__ ub2,
                            u32* __restrict__ ws) {
    int t = blockIdx.x * blockDim.x + threadIdx.x;
    if (t >= 15936) return;
    if (t >= 15872) {
        // ---- dist-row weights, packed bf16 ----
        int i = t - 15872;                    // [0, 64)
        ws[63488 + i] = pack2(mw1[256 * H + 2 * i], mw1[256 * H + 2 * i + 1]);
        return;
    }
    if (t >= 13312) {
        // ---- 16x16 A-frags of msg w2 ----
        int slot = t - 13312;                 // (kb*8 + mt)*64 + lane
        int lane = slot & 63, fb = slot >> 6;
        int kb = fb >> 3, mt = fb & 7;
        int m = mt * 16 + (lane & 15);
        int quad = lane >> 4;
        u32 out[4];
        #pragma unroll
        for (int p = 0; p < 4; ++p) {
            float v[2];
            #pragma unroll
            for (int h = 0; h < 2; ++h) {
                int k = kb * 32 + quad * 8 + p * 2 + h;
                float val = 0.0f;
                if (k < 128)       val = mw2[(size_t)k * H + m];
                else if (k == 128) val = mb2[m];
                v[h] = val;
            }
            out[p] = pack2(v[0], v[1]);
        }
        u32* dst = ws + 53248 + (size_t)slot * 4;
        dst[0] = out[0]; dst[1] = out[1]; dst[2] = out[2]; dst[3] = out[3];
        return;
    }
    const float *W, *s0, *s1;
    int nK, slot, base;
    if (t < 4352)       { W = mw1; s0 = mw1 + 256 * H; s1 = mb1; nK = 256; slot = t;         base = 0;     }
    else if (t < 6656)  { W = mw2; s0 = mb2; s1 = nullptr;       nK = 128; slot = t - 4352;  base = 17408; }
    else if (t < 11008) { W = uw1; s0 = ub1; s1 = nullptr;       nK = 256; slot = t - 6656;  base = 26624; }
    else                { W = uw2; s0 = ub2; s1 = nullptr;       nK = 128; slot = t - 11008; base = 44032; }
    int lane = slot & 63, fb = slot >> 6;
    int ct, kb;
    if (nK == 256) { ct = fb / 17; kb = fb % 17; }
    else           { ct = fb / 9;  kb = fb % 9;  }
    int m = ct * 32 + (lane & 31);
    int q = lane >> 5;
    u32 out[4];
    #pragma unroll
    for (int p = 0; p < 4; ++p) {
        float v[2];
        #pragma unroll
        for (int h = 0; h < 2; ++h) {
            int k = kb * 16 + q * 8 + p * 2 + h;
            float val = 0.0f;
            if (k < nK)            val = W[(size_t)k * H + m];
            else if (k == nK)      val = s0 ? s0[m] : 0.0f;
            else if (k == nK + 1)  val = s1 ? s1[m] : 0.0f;
            v[h] = val;
        }
        out[p] = pack2(v[0], v[1]);
    }
    u32* dst = ws + base + (size_t)slot * 4;
    dst[0] = out[0]; dst[1] = out[1]; dst[2] = out[2]; dst[3] = out[3];
}

// ---------------------------------------------------------------------------
// front_kernel (R15: FOUR parallel jobs — R9's parallel fusion, extended):
//   blocks [0, PQB)        : P GEMM  (x @ mw1[0:128], packed bf16 -> Pb)
//   blocks [PQB, 2*PQB)    : Q GEMM  (x @ mw1[128:256] + b1, packed -> Qb)
//   blocks [2*PQB, 3*PQB)  : U GEMM  (x @ uw1[0:128], packed -> Ub)
//   blocks [3*PQB, +BKB)   : bucket_fill (grid-stride over E edges)
// ---------------------------------------------------------------------------
__global__ __launch_bounds__(256, 2) void front_kernel(
    const float* __restrict__ x, const u32* __restrict__ ws,
    u32* __restrict__ Pb, u32* __restrict__ Qb, u32* __restrict__ Ub,
    const float* __restrict__ pos, const int* __restrict__ ei,
    int* __restrict__ deg, int2* __restrict__ bucket,
    int N, int E, int nIter, int PQB, int BKB)
{
    const int b = blockIdx.x;
    if (b < 3 * PQB) {
        // ---- P / Q / U GEMM (pq_gemm body, 32 nodes/wave) ----
        const int job = b / PQB;                 // 0=P, 1=Q, 2=U
        const int bb = b - job * PQB;
        const int kbBase = (job == 1) ? 8 : 0;
        const u32* wt = (job == 2) ? (ws + 26624) : ws;   // U uses uw1 frags
        u32* outb = (job == 0) ? Pb : ((job == 1) ? Qb : Ub);

        const int lane = threadIdx.x & 63;
        const int q = lane >> 5, el = lane & 31;
        const int gw  = bb * 4 + (threadIdx.x >> 6);
        const int gws = PQB * 4;

        for (int it = gw; it < nIter; it += gws) {
            const int nA = it * 32 + el;
            const int ncA = (nA < N) ? nA : (N - 1);
            const float* xA = x + (size_t)ncA * H;

            f32x16 acc[4];
            #pragma unroll
            for (int ct = 0; ct < 4; ++ct) acc[ct] = (f32x16)0.0f;

            #pragma unroll
            for (int kb = 0; kb < 8; ++kb) {
                const int f = kb * 16 + q * 8;
                bf16x8 bA = f8frag(*(const float4*)(xA + f), *(const float4*)(xA + f + 4));
                #pragma unroll
                for (int ct = 0; ct < 4; ++ct) {
                    Frag a; a.u = *(const u32x4*)&wt[((size_t)(ct * 17 + kbBase + kb) * 64 + lane) * 4];
                    acc[ct] = mfma(a.b, bA, acc[ct]);
                }
            }
            if (job == 1) {   // Q bias: pad kb16 (k=256 -> 0 skip dist, k=257 -> 1.0 b1)
                Frag bp; bp.u = (u32x4){0, 0, 0, 0};
                if (q == 0) bp.u.x = pack2(0.0f, 1.0f);
                #pragma unroll
                for (int ct = 0; ct < 4; ++ct) {
                    Frag a; a.u = *(const u32x4*)&ws[((size_t)(ct * 17 + 16) * 64 + lane) * 4];
                    acc[ct] = mfma(a.b, bp.b, acc[ct]);
                }
            }
            if (nA < N) {
                u32* prow = outb + (size_t)nA * 64;
                #pragma unroll
                for (int ct = 0; ct < 4; ++ct)
                    #pragma unroll
                    for (int g = 0; g < 4; ++g) {
                        u32 a = pack2(acc[ct][4*g + 0], acc[ct][4*g + 1]);
                        u32 bb2 = pack2(acc[ct][4*g + 2], acc[ct][4*g + 3]);
                        *(uint2*)(prow + ct * 16 + 4 * g + 2 * q) = make_uint2(a, bb2);
                    }
            }
        }
    } else {
        // ---- bucket_fill: grid-stride over edges ----
        const int bb = b - 3 * PQB;
        for (int e = bb * 256 + (int)threadIdx.x; e < E; e += BKB * 256) {
            const int s = ei[e];
            const int r = ei[E + e];
            const float dx = pos[s*3]   - pos[r*3];
            const float dy = pos[s*3+1] - pos[r*3+1];
            const float dz = pos[s*3+2] - pos[r*3+2];
            const float dist = sqrtf(dx*dx + dy*dy + dz*dz);
            int slot = atomicAdd(&deg[r], 1);
            if (slot < 64) bucket[(size_t)r * 64 + slot] = make_int2(s, __float_as_int(dist));
        }
    }
}

// ---------------------------------------------------------------------------
// One 16-edge tile of the aggregate: acc init = b2, 4 kb steps of
// h=silu(P+Q+dist*wd) -> MFMA, masked silu accumulation into sum.
// ---------------------------------------------------------------------------
__device__ __forceinline__ void agg_tile(
    const u32x4 pc[4], const u32x4* __restrict__ Qrow,
    const u32x4* __restrict__ wds, const u32x4* __restrict__ af,
    const float* __restrict__ b2s, float dist, bool valid,
    int lane, int quad, f32x4 sum[8])
{
    f32x4 acc[8];
    #pragma unroll
    for (int mt = 0; mt < 8; ++mt)
        acc[mt] = *(const f32x4*)&b2s[mt * 16 + quad * 4];

    #pragma unroll 2
    for (int kb = 0; kb < 4; ++kb) {
        const u32x4 p = pc[kb];
        const u32x4 qc = Qrow[kb * 4 + quad];
        const u32x4 wc = wds[kb * 4 + quad];
        const float v0 = silu(bflo(p.x) + bflo(qc.x) + dist * bflo(wc.x));
        const float v1 = silu(bfhi(p.x) + bfhi(qc.x) + dist * bfhi(wc.x));
        const float v2 = silu(bflo(p.y) + bflo(qc.y) + dist * bflo(wc.y));
        const float v3 = silu(bfhi(p.y) + bfhi(qc.y) + dist * bfhi(wc.y));
        const float v4 = silu(bflo(p.z) + bflo(qc.z) + dist * bflo(wc.z));
        const float v5 = silu(bfhi(p.z) + bfhi(qc.z) + dist * bfhi(wc.z));
        const float v6 = silu(bflo(p.w) + bflo(qc.w) + dist * bflo(wc.w));
        const float v7 = silu(bfhi(p.w) + bfhi(qc.w) + dist * bfhi(wc.w));
        Frag bf;
        bf.u = (u32x4){pack2(v0, v1), pack2(v2, v3), pack2(v4, v5), pack2(v6, v7)};
        if (!valid) bf.u = (u32x4){0, 0, 0, 0};
        #pragma unroll
        for (int mt = 0; mt < 8; ++mt) {
            Frag a; a.u = af[(kb * 8 + mt) * 64 + lane];
            acc[mt] = mfma16(a.b, bf.b, acc[mt]);
        }
    }
    #pragma unroll
    for (int mt = 0; mt < 8; ++mt) {
        sum[mt][0] += valid ? silu(acc[mt][0]) : 0.0f;
        sum[mt][1] += valid ? silu(acc[mt][1]) : 0.0f;
        sum[mt][2] += valid ? silu(acc[mt][2]) : 0.0f;
        sum[mt][3] += valid ? silu(acc[mt][3]) : 0.0f;
    }
}

// ---------------------------------------------------------------------------
// aggregate (16x16, R17): ONE node per wave + cross-node P-ROW PREFETCH.
// R16's 2-node ILP spilled (sumA+sumB+acc+pcB ~140 arch > bounds-3 cap;
// WRITE 177 MB, 208 us -> reverted). Same mechanism, 1/4 the registers:
// mean degree 12.8 => ~85% of nodes have nt=1, so the serial chain is
// node-to-node: deg -> bucket -> P-gather -> compute. R6 prefetched only
// deg+bucket (null); the P-gather (longest hop, ~400-900cy) stayed serial.
// Pipeline (1-deep): at node i issue deg+bucket for i+1 early; after tile-0
// compute (bucket reply hidden under it) issue i+1's P-rows (pc_pf, 16 regs);
// they fly across reduce+store+loop-turn. Requires bucket pre-zero
// (unclamped t=0 read; stale slots (0,0) masked by valid).
// Peak live ~115 regs < ~170 cap. Sentinels: VGPR <= ~130, WRITE 12.5 MB.
// ---------------------------------------------------------------------------
__global__ __launch_bounds__(256, 3) void aggregate_kernel(
    const u32* __restrict__ Pbf, const u32* __restrict__ Qbf,
    const u32* __restrict__ wdp, const u32* __restrict__ ws16,
    const float* __restrict__ mb2,
    const int* __restrict__ deg, const int2* __restrict__ bucket,
    u32* __restrict__ aggrp, int N)
{
    __shared__ u32x4 af[2048];                        // 32 KiB: w2 16x16 A-frags
    __shared__ float b2s[128];                        // b2 fp32 (C-init source)
    __shared__ u32x4 wds[16];                         // dist-row weights (packed bf16)
    for (int i = threadIdx.x; i < 2048; i += 256) af[i] = ((const u32x4*)ws16)[i];
    for (int i = threadIdx.x; i < 128; i += 256) b2s[i] = mb2[i];
    if (threadIdx.x < 16) wds[threadIdx.x] = ((const u32x4*)wdp)[threadIdx.x];
    __syncthreads();

    const int lane = threadIdx.x & 63;
    const int quad = lane >> 4, col = lane & 15;

    const int gw  = blockIdx.x * 4 + (threadIdx.x >> 6);
    const int gws = gridDim.x * 4;

    // ---- pipeline state: next node's deg, t=0 bucket rec, and P rows ----
    int n = gw;
    int dn_pf = 0;
    int2 rec_pf = make_int2(0, 0);
    u32x4 pc_pf[4];
    #pragma unroll
    for (int kb = 0; kb < 4; ++kb) pc_pf[kb] = (u32x4){0, 0, 0, 0};
    if (n < N) {
        dn_pf  = deg[n];
        rec_pf = bucket[(size_t)n * 64 + col];        // unclamped (pre-zeroed)
        const u32x4* Pr = (const u32x4*)(Pbf + (size_t)rec_pf.x * 64);
        #pragma unroll
        for (int kb = 0; kb < 4; ++kb) pc_pf[kb] = Pr[kb * 4 + quad];
    }

    for (; n < N; n += gws) {
        int dn = dn_pf; dn = (dn > 64) ? 64 : dn;
        const int nt = (dn + 15) >> 4;
        const float dist0 = __int_as_float(rec_pf.y);
        u32x4 pc0[4];
        #pragma unroll
        for (int kb = 0; kb < 4; ++kb) pc0[kb] = pc_pf[kb];

        // issue next node's deg + bucket row NOW (reply hides under compute)
        const int nn = n + gws;
        if (nn < N) {
            dn_pf  = deg[nn];
            rec_pf = bucket[(size_t)nn * 64 + col];
        }

        const u32x4* Qrow = (const u32x4*)(Qbf + (size_t)n * 64);

        f32x4 sum[8];
        #pragma unroll
        for (int mt = 0; mt < 8; ++mt) sum[mt] = (f32x4){0.f, 0.f, 0.f, 0.f};

        // ---- tile 0: all data prefetched ----
        agg_tile(pc0, Qrow, wds, af, b2s, dist0, col < dn, lane, quad, sum);

        // ---- remaining tiles (rare; ~15% of nodes): serial ----
        for (int t = 1; t < nt; ++t) {
            const int eIdx = t * 16 + col;
            const bool valid = eIdx < dn;
            const int eC = valid ? eIdx : (dn - 1);
            const int2 rec = bucket[(size_t)n * 64 + eC];
            const u32x4* Pr = (const u32x4*)(Pbf + (size_t)rec.x * 64);
            u32x4 pc[4];
            #pragma unroll
            for (int kb = 0; kb < 4; ++kb) pc[kb] = Pr[kb * 4 + quad];
            agg_tile(pc, Qrow, wds, af, b2s, __int_as_float(rec.y), valid, lane, quad, sum);
        }

        // issue next node's P-row gather (rec_pf arrived under compute);
        // loads fly across the reduce + store + loop turn.
        if (nn < N) {
            const u32x4* Pr = (const u32x4*)(Pbf + (size_t)rec_pf.x * 64);
            #pragma unroll
            for (int kb = 0; kb < 4; ++kb) pc_pf[kb] = Pr[kb * 4 + quad];
        }

        // reduce over the 16 column-lanes: DPP row rotations, pure VALU
        #pragma unroll
        for (int mt = 0; mt < 8; ++mt)
            #pragma unroll
            for (int r = 0; r < 4; ++r) {
                float v = sum[mt][r];
                DPP_RADD(v, 0x128);   // row_ror:8
                DPP_RADD(v, 0x124);   // row_ror:4
                DPP_RADD(v, 0x122);   // row_ror:2
                DPP_RADD(v, 0x121);   // row_ror:1
                sum[mt][r] = v;
            }
        if (col == 0) {               // lanes 0,16,32,48: dims mt*16+quad*4+j
            u32* orow = aggrp + (size_t)n * 64;
            #pragma unroll
            for (int mt = 0; mt < 8; ++mt) {
                u32 a = pack2(sum[mt][0], sum[mt][1]);
                u32 b = pack2(sum[mt][2], sum[mt][3]);
                *(uint2*)(orow + mt * 8 + quad * 2) = make_uint2(a, b);
            }
        }
    }
}

// ---------------------------------------------------------------------------
// node1_slim (R15): h = silu(U + aggr @ uw1[128:256] + b1) -> packed bf16.
// ---------------------------------------------------------------------------
__global__ __launch_bounds__(256, 2) void node1_slim(
    const u32* __restrict__ aggrp, const u32* __restrict__ Ub,
    const u32* __restrict__ ws, u32* __restrict__ Hb, int N, int nIter)
{
    __shared__ u32 lds[8192];                         // uw1 kb 8..15 frags (32 KiB)
    const u32* wsl1 = ws + 26624;
    {
        const u32x4* src = (const u32x4*)wsl1;
        u32x4* dst = (u32x4*)lds;
        for (int i = threadIdx.x; i < 2048; i += 256) {
            int ln = i & 63, fb = i >> 6, ct = fb >> 3, kb = fb & 7;
            dst[i] = src[(ct * 17 + 8 + kb) * 64 + ln];
        }
    }
    __syncthreads();

    const int lane = threadIdx.x & 63;
    const int q = lane >> 5, el = lane & 31;
    const int gw  = blockIdx.x * 4 + (threadIdx.x >> 6);
    const int gws = gridDim.x * 4;

    for (int it = gw; it < nIter; it += gws) {
        const int nA = it * 32 + el;
        const int ncA = (nA < N) ? nA : (N - 1);
        const u32* arow = aggrp + (size_t)ncA * 64;
        const u32* Urow = Ub + (size_t)ncA * 64;

        f32x16 acc[4];
        #pragma unroll
        for (int ct = 0; ct < 4; ++ct) acc[ct] = (f32x16)0.0f;

        #pragma unroll
        for (int kb = 0; kb < 8; ++kb) {
            Frag hb; hb.u = *(const u32x4*)&arow[kb * 8 + q * 4];
            #pragma unroll
            for (int ct = 0; ct < 4; ++ct) {
                Frag a; a.u = *(const u32x4*)&lds[((ct * 8 + kb) * 64 + lane) * 4];
                acc[ct] = mfma(a.b, hb.b, acc[ct]);
            }
        }
        {   // bias: k=256 -> 1.0 (b1)
            Frag bp; bp.u = (u32x4){0,0,0,0};
            if (q == 0) bp.u.x = 0x00003F80u;
            #pragma unroll
            for (int ct = 0; ct < 4; ++ct) {
                Frag a; a.u = *(const u32x4*)&wsl1[((size_t)(ct * 17 + 16) * 64 + lane) * 4];
                acc[ct] = mfma(a.b, bp.b, acc[ct]);
            }
        }
        if (nA < N) {
            u32* hrow = Hb + (size_t)nA * 64;
            #pragma unroll
            for (int ct = 0; ct < 4; ++ct)
                #pragma unroll
                for (int g = 0; g < 4; ++g) {
                    uint2 uv = *(const uint2*)&Urow[ct * 16 + 4 * g + 2 * q];
                    u32 a = pack2(silu(acc[ct][4*g + 0] + bflo(uv.x)),
                                  silu(acc[ct][4*g + 1] + bfhi(uv.x)));
                    u32 b = pack2(silu(acc[ct][4*g + 2] + bflo(uv.y)),
                                  silu(acc[ct][4*g + 3] + bfhi(uv.y)));
                    *(uint2*)(hrow + ct * 16 + 4 * g + 2 * q) = make_uint2(a, b);
                }
        }
    }
}

// ---------------------------------------------------------------------------
// node1_full (fallback path only): h = silu([x,aggr]@uw1+b1), f32 aggr input.
// ---------------------------------------------------------------------------
__global__ __launch_bounds__(256, 2) void node1_full(
    const float* __restrict__ x, const float* __restrict__ aggr,
    const u32* __restrict__ ws, u32* __restrict__ Hb, int N, int nIter)
{
    __shared__ u32 lds[16384];
    const u32* wsl1 = ws + 26624;
    {
        const u32x4* src = (const u32x4*)wsl1;
        u32x4* dst = (u32x4*)lds;
        for (int i = threadIdx.x; i < 4096; i += 256) {
            int ln = i & 63, fb = i >> 6, ct = fb >> 4, kb = fb & 15;
            dst[i] = src[(ct * 17 + kb) * 64 + ln];
        }
    }
    __syncthreads();

    const int lane = threadIdx.x & 63;
    const int q = lane >> 5, el = lane & 31;
    const int gw  = blockIdx.x * 4 + (threadIdx.x >> 6);
    const int gws = gridDim.x * 4;

    for (int it = gw; it < nIter; it += gws) {
        const int nA = it * 32 + el;
        const int ncA = (nA < N) ? nA : (N - 1);
        const float* xA = x + (size_t)ncA * H;
        const float* gA = aggr + (size_t)ncA * H;

        f32x16 acc[4];
        #pragma unroll
        for (int ct = 0; ct < 4; ++ct) acc[ct] = (f32x16)0.0f;

        #pragma unroll
        for (int kb = 0; kb < 16; ++kb) {
            const int f = kb * 16 + q * 8;
            const float* pA = (f < H) ? (xA + f) : (gA + f - H);
            bf16x8 bA = f8frag(*(const float4*)pA, *(const float4*)(pA + 4));
            #pragma unroll
            for (int ct = 0; ct < 4; ++ct) {
                Frag a; a.u = *(const u32x4*)&lds[((ct * 16 + kb) * 64 + lane) * 4];
                acc[ct] = mfma(a.b, bA, acc[ct]);
            }
        }
        {
            Frag bp; bp.u = (u32x4){0,0,0,0};
            if (q == 0) bp.u.x = 0x00003F80u;
            #pragma unroll
            for (int ct = 0; ct < 4; ++ct) {
                Frag a; a.u = *(const u32x4*)&wsl1[((size_t)(ct * 17 + 16) * 64 + lane) * 4];
                acc[ct] = mfma(a.b, bp.b, acc[ct]);
            }
        }
        if (nA < N) {
            u32* hrow = Hb + (size_t)nA * 64;
            #pragma unroll
            for (int ct = 0; ct < 4; ++ct)
                #pragma unroll
                for (int g = 0; g < 4; ++g) {
                    u32 a = pack2(silu(acc[ct][4*g + 0]), silu(acc[ct][4*g + 1]));
                    u32 b = pack2(silu(acc[ct][4*g + 2]), silu(acc[ct][4*g + 3]));
                    *(uint2*)(hrow + ct * 16 + 4 * g + 2 * q) = make_uint2(a, b);
                }
        }
    }
}

// ---------------------------------------------------------------------------
// node2: update = h @ uw2 + b2 -> out (f32). B-frag = one u32x4 row load.
// ---------------------------------------------------------------------------
__global__ __launch_bounds__(256, 2) void node2_kernel(
    const u32* __restrict__ Hb, const u32* __restrict__ ws,
    float* __restrict__ out, int N, int nIter)
{
    const u32* wsl2 = ws + 44032;
    const int lane = threadIdx.x & 63;
    const int q = lane >> 5, el = lane & 31;
    const int gw  = blockIdx.x * 4 + (threadIdx.x >> 6);
    const int gws = gridDim.x * 4;

    for (int it = gw; it < nIter; it += gws) {
        const int nA = it * 32 + el;
        const int ncA = (nA < N) ? nA : (N - 1);
        const u32* hrow = Hb + (size_t)ncA * 64;

        f32x16 acc[4];
        #pragma unroll
        for (int ct = 0; ct < 4; ++ct) acc[ct] = (f32x16)0.0f;

        #pragma unroll
        for (int kb = 0; kb < 8; ++kb) {
            Frag hb; hb.u = *(const u32x4*)&hrow[kb * 8 + q * 4];
            #pragma unroll
            for (int ct = 0; ct < 4; ++ct) {
                Frag a; a.u = *(const u32x4*)&wsl2[((size_t)(ct * 9 + kb) * 64 + lane) * 4];
                acc[ct] = mfma(a.b, hb.b, acc[ct]);
            }
        }
        {   // bias: k=128 -> 1.0 (b2)
            Frag bf; bf.u = (u32x4){0,0,0,0};
            if (q == 0) bf.u.x = 0x00003F80u;
            #pragma unroll
            for (int ct = 0; ct < 4; ++ct) {
                Frag a; a.u = *(const u32x4*)&wsl2[((size_t)(ct * 9 + 8) * 64 + lane) * 4];
                acc[ct] = mfma(a.b, bf.b, acc[ct]);
            }
        }
        if (nA < N) {
            float* orow = out + (size_t)nA * H;
            #pragma unroll
            for (int ct = 0; ct < 4; ++ct)
                #pragma unroll
                for (int g = 0; g < 4; ++g) {
                    float4 v = { acc[ct][4*g + 0], acc[ct][4*g + 1],
                                 acc[ct][4*g + 2], acc[ct][4*g + 3] };
                    *(float4*)(orow + ct * 32 + 8 * g + 4 * q) = v;
                }
        }
    }
}

// ---------------------------------------------------------------------------
// FALLBACK (ws too small): edge kernel with fp32 atomics.
// ---------------------------------------------------------------------------
__global__ __launch_bounds__(256, 2) void edge_mfma(
    const float* __restrict__ x, const float* __restrict__ pos,
    const int* __restrict__ ei, const u32* __restrict__ ws,
    float* __restrict__ aggr, int E, int nIter)
{
    __shared__ u32 lds[16384];
    {
        const u32x4* src = (const u32x4*)ws;
        u32x4* dst = (u32x4*)lds;
        for (int i = threadIdx.x; i < 4096; i += 256) {
            int ln = i & 63, fb = i >> 6, ct = fb >> 4, kb = fb & 15;
            dst[i] = src[(ct * 17 + kb) * 64 + ln];
        }
    }
    __syncthreads();
    const u32* wsl1 = ws;
    const u32* wsl2 = ws + 17408;

    const int lane = threadIdx.x & 63;
    const int q = lane >> 5, el = lane & 31;
    const int gw  = blockIdx.x * 4 + (threadIdx.x >> 6);
    const int gws = gridDim.x * 4;

    for (int it = gw; it < nIter; it += gws) {
        const int e0 = it * 64;
        const int sA = ei[e0 + el],      rA = ei[E + e0 + el];
        const int sB = ei[e0 + 32 + el], rB = ei[E + e0 + 32 + el];
        float dA, dB;
        {
            float ax = pos[sA*3] - pos[rA*3], ay = pos[sA*3+1] - pos[rA*3+1], az = pos[sA*3+2] - pos[rA*3+2];
            dA = sqrtf(ax*ax + ay*ay + az*az);
            float bx = pos[sB*3] - pos[rB*3], by = pos[sB*3+1] - pos[rB*3+1], bz = pos[sB*3+2] - pos[rB*3+2];
            dB = sqrtf(bx*bx + by*by + bz*bz);
        }
        const float* xsA = x + (size_t)sA * H; const float* xrA = x + (size_t)rA * H;
        const float* xsB = x + (size_t)sB * H; const float* xrB = x + (size_t)rB * H;

        f32x16 acc[2][4];
        #pragma unroll
        for (int s = 0; s < 2; ++s)
            #pragma unroll
            for (int ct = 0; ct < 4; ++ct) acc[s][ct] = (f32x16)0.0f;

        #pragma unroll
        for (int kb = 0; kb < 16; ++kb) {
            const int f = kb * 16 + q * 8;
            const float* pA = (f < H) ? (xsA + f) : (xrA + f - H);
            const float* pB = (f < H) ? (xsB + f) : (xrB + f - H);
            bf16x8 bA = f8frag(*(const float4*)pA, *(const float4*)(pA + 4));
            bf16x8 bB = f8frag(*(const float4*)pB, *(const float4*)(pB + 4));
            #pragma unroll
            for (int ct = 0; ct < 4; ++ct) {
                Frag a; a.u = *(const u32x4*)&lds[((ct * 16 + kb) * 64 + lane) * 4];
                acc[0][ct] = mfma(a.b, bA, acc[0][ct]);
                acc[1][ct] = mfma(a.b, bB, acc[1][ct]);
            }
        }
        {
            Frag bA, bB;
            bA.u = (u32x4){0,0,0,0}; bB.u = (u32x4){0,0,0,0};
            if (q == 0) { bA.u.x = pack2(dA, 1.0f); bB.u.x = pack2(dB, 1.0f); }
            #pragma unroll
            for (int ct = 0; ct < 4; ++ct) {
                Frag a; a.u = *(const u32x4*)&wsl1[((size_t)(ct * 17 + 16) * 64 + lane) * 4];
                acc[0][ct] = mfma(a.b, bA.b, acc[0][ct]);
                acc[1][ct] = mfma(a.b, bB.b, acc[1][ct]);
            }
        }

        #pragma unroll
        for (int s = 0; s < 2; ++s) {
            const int ridx = s ? rB : rA;
            u32 hp[16][2];
            #pragma unroll
            for (int ct = 0; ct < 4; ++ct)
                #pragma unroll
                for (int g = 0; g < 4; ++g) {
                    hp[ct * 4 + g][0] = pack2(silu(acc[s][ct][4*g + 0]), silu(acc[s][ct][4*g + 1]));
                    hp[ct * 4 + g][1] = pack2(silu(acc[s][ct][4*g + 2]), silu(acc[s][ct][4*g + 3]));
                }

            f32x16 acc2[4];
            #pragma unroll
            for (int ct = 0; ct < 4; ++ct) acc2[ct] = (f32x16)0.0f;

            #pragma unroll
            for (int kb2 = 0; kb2 < 8; ++kb2) {
                const u32 e0v = hp[2 * kb2][0],     e1v = hp[2 * kb2][1];
                const u32 o0v = hp[2 * kb2 + 1][0], o1v = hp[2 * kb2 + 1][1];
                const u32 w0  = q ? o0v : e0v;
                const u32 w1v = q ? o1v : e1v;
                const u32 sv0 = q ? e0v : o0v;
                const u32 sv1 = q ? e1v : o1v;
                u32 r0 = (u32)__shfl((int)sv0, lane ^ 32);
                u32 r1 = (u32)__shfl((int)sv1, lane ^ 32);
                Frag bf;
                if (q == 0) bf.u = (u32x4){w0, w1v, r0, r1};
                else        bf.u = (u32x4){r0, r1, w0, w1v};
                #pragma unroll
                for (int ct2 = 0; ct2 < 4; ++ct2) {
                    Frag a; a.u = *(const u32x4*)&wsl2[((size_t)(ct2 * 9 + kb2) * 64 + lane) * 4];
                    acc2[ct2] = mfma(a.b, bf.b, acc2[ct2]);
                }
            }
            {
                Frag bf; bf.u = (u32x4){0,0,0,0};
                if (q == 0) bf.u.x = 0x00003F80u;
                #pragma unroll
                for (int ct2 = 0; ct2 < 4; ++ct2) {
                    Frag a; a.u = *(const u32x4*)&wsl2[((size_t)(ct2 * 9 + 8) * 64 + lane) * 4];
                    acc2[ct2] = mfma(a.b, bf.b, acc2[ct2]);
                }
            }
            float* arow = aggr + (size_t)ridx * H;
            #pragma unroll
            for (int ct2 = 0; ct2 < 4; ++ct2)
                #pragma unroll
                for (int r = 0; r < 16; ++r) {
                    int m = ct2 * 32 + (r & 3) + 8 * (r >> 2) + 4 * q;
                    atomicAdd(arow + m, silu(acc2[ct2][r]));
                }
        }
    }
}

extern "C" void kernel_launch(void* const* d_in, const int* in_sizes, int n_in,
                              void* d_out, int out_size, void* d_ws, size_t ws_size,
                              hipStream_t stream) {
    const float* x    = (const float*)d_in[0];
    const float* pos  = (const float*)d_in[1];
    const int*   ei   = (const int*)d_in[2];
    const float* mw1  = (const float*)d_in[3];
    const float* mb1  = (const float*)d_in[4];
    const float* mw2  = (const float*)d_in[5];
    const float* mb2  = (const float*)d_in[6];
    const float* uw1  = (const float*)d_in[7];
    const float* ub1  = (const float*)d_in[8];
    const float* uw2  = (const float*)d_in[9];
    const float* ub2  = (const float*)d_in[10];

    const int N = in_sizes[0] / H;
    const int E = in_sizes[2] / 2;

    // ws layout (u32 units) — unchanged (U lives in d_out high half)
    const size_t FRAGS = 53248 + 10240 + 64;     // 32x32 frags + 16x16 frags + wdp
    const size_t PO = FRAGS;                     // P: N*64 u32 (packed bf16 rows)
    const size_t QO = PO + (size_t)N * 64;       // Q: N*64 u32 (packed bf16 rows)
    const size_t DG = QO + (size_t)N * 64;       // deg: N int
    const size_t BK = DG + (size_t)N;            // bucket: N*64 int2
    const size_t ENDu = BK + (size_t)N * 128;
    const size_t need_bytes = ENDu * 4;

    u32* ws = (u32*)d_ws;
    prep_kernel<<<63, 256, 0, stream>>>(mw1, mb1, mw2, mb2, uw1, ub1, uw2, ub2, ws);

    float* buf = (float*)d_out;
    u32* bufu = (u32*)d_out;
    const int nIter32 = (N + 31) / 32;           // 32 nodes per wave

    if (ws_size >= need_bytes) {
        // ---- gather path: no fp32 atomics ----
        u32*   Pb    = ws + PO;
        u32*   Qb    = ws + QO;
        int*   deg   = (int*)(ws + DG);
        int2*  bkt   = (int2*)(ws + BK);
        u32*   aggrp = bufu;                     // low half of d_out (packed aggr)
        u32*   Ub    = bufu + (size_t)N * 64;    // high half of d_out (packed U)

        // zero deg AND bucket: aggregate's prefetch reads bucket t=0 slots
        // unclamped (stale slots must be (0,0) -> masked row-0 gather).
        hipMemsetAsync(deg, 0, (size_t)N * sizeof(int), stream);
        hipMemsetAsync(bkt, 0, (size_t)N * 64 * sizeof(int2), stream);

        // P || Q || U GEMMs || bucket_fill, one launch (parallel fusion)
        const int PQB = 392;                     // 392*4 = 1568 waves >= 1563 iters
        const int BKB = 640;
        front_kernel<<<3 * PQB + BKB, 256, 0, stream>>>(
            x, ws, Pb, Qb, Ub, pos, ei, deg, bkt, N, E, nIter32, PQB, BKB);

        // P-prefetch-pipelined aggregate: 768 blocks = exactly 3/CU at (256,3)
        aggregate_kernel<<<768, 256, 0, stream>>>(Pb, Qb, ws + 63488, ws + 53248,
                                                  mb2, deg, bkt, aggrp, N);

        // slim node MLP: h = silu(U + aggr@uw1[128:] + b1); update = h@uw2+b2
        node1_slim<<<512, 256, 0, stream>>>(aggrp, Ub, ws, Pb, N, nIter32);
        node2_kernel<<<512, 256, 0, stream>>>(Pb, ws, buf, N, nIter32);
    } else {
        // ---- fallback: atomic scatter path + full node MLP ----
        hipMemsetAsync(buf, 0, (size_t)N * H * sizeof(float), stream);
        edge_mfma<<<512, 256, 0, stream>>>(x, pos, ei, ws, buf, E, E / 64);
        node1_full<<<512, 256, 0, stream>>>(x, buf, ws, ws + PO, N, nIter32);
        node2_kernel<<<512, 256, 0, stream>>>(ws + PO, ws, buf, N, nIter32);
    }
}